// Round 8
// baseline (171.497 us; speedup 1.0000x reference)
//
#include <hip/hip_runtime.h>
#include <hip/hip_bf16.h>
#include <stdint.h>

// Attention fwd: B=2, N=2048, D=768, H=12, Dh=64, INNER=768
// R20 = R19 (attn_k/prep_k byte-identical, XCD panel remap kept) + gemms
// restructured to A-IN-REGISTERS: A fragments are reused by only 2 waves, so
// the LDS round-trip (8KB DMA + 16KB reads per block-iter) is waste. Each
// wave now loads its own A frags global->VGPR (L2-hot after XCD grouping),
// double-buffered 2 tiles ahead in areg[it&1][] (static idx). LDS holds only
// B (3 x 6KB). Per-iter ds_reads 7->3, DMA 3->1.5, A->MFMA is reg-direct.
// Counted vmcnt re-derived for merged reg-load/DMA FIFO (issue order per
// iter: MFMA -> B-DMA -> A-reg-loads):
//   qkv steady: stack B(t+1),A(t+1),B(t+2),A(t+2) = w01 2/4/2/4 -> vmcnt(10)
//               w23 1/4/1/4 -> vmcnt(9); prologue w01 vmcnt(6) / w23 (5).
//   out steady: w01 2/2/2/2 -> vmcnt(6), w23 1/2/1/2 -> vmcnt(5);
//               prologue w01 vmcnt(4) / w23 (3).

typedef __attribute__((ext_vector_type(8))) short bf16x8;
typedef __attribute__((ext_vector_type(4))) float f32x4;
typedef __attribute__((address_space(3))) unsigned int lds_uint;
typedef __attribute__((address_space(1))) const unsigned int g_uint;

__device__ __forceinline__ short f2bf(float f) {
    union { float f; uint32_t u; } x; x.f = f;
    uint32_t r = (x.u + 0x7fffu + ((x.u >> 16) & 1u)) >> 16;
    return (short)r;
}
__device__ __forceinline__ float exp2fast(float x) {
#if __has_builtin(__builtin_amdgcn_exp2f)
    return __builtin_amdgcn_exp2f(x);
#else
    return __expf(x * 0.6931471805599453f);
#endif
}
__device__ __forceinline__ void gl_lds16(const void* g, void* l) {
    __builtin_amdgcn_global_load_lds((g_uint*)g, (lds_uint*)l, 16, 0, 0);
}
#define WAITCNT_VM(N) asm volatile("s_waitcnt vmcnt(" #N ")" ::: "memory")
#define BARRIER_FENCED() do { __builtin_amdgcn_s_barrier(); \
                              asm volatile("" ::: "memory"); } while (0)

// ---------------------------------------------------------------------------
// 64x64 fp32->bf16 transpose tile (shared by prep_k / tr_w)
// ---------------------------------------------------------------------------
__device__ __forceinline__ void tr_tile(const float* __restrict__ W,
                                        short* __restrict__ Wt, int K, int N,
                                        int n0, int k0, int t, short* S) {
    {
        int kl = t >> 2, ng = t & 3;
        const float* src = W + (size_t)(k0 + kl) * N + n0 + ng * 16;
        #pragma unroll
        for (int j = 0; j < 16; j += 4) {
            float4 f = *(const float4*)(src + j);
            S[(ng*16 + j + 0) * 65 + kl] = f2bf(f.x);
            S[(ng*16 + j + 1) * 65 + kl] = f2bf(f.y);
            S[(ng*16 + j + 2) * 65 + kl] = f2bf(f.z);
            S[(ng*16 + j + 3) * 65 + kl] = f2bf(f.w);
        }
    }
    __syncthreads();
    {
        int nl = t >> 2, kg = t & 3;
        short* dst = Wt + (size_t)(n0 + nl) * K + k0 + kg * 16;
        #pragma unroll
        for (int j = 0; j < 16; j += 4) {
            short4 s4;
            s4.x = S[nl*65 + kg*16 + j + 0];
            s4.y = S[nl*65 + kg*16 + j + 1];
            s4.z = S[nl*65 + kg*16 + j + 2];
            s4.w = S[nl*65 + kg*16 + j + 3];
            *(short4*)(dst + j) = s4;
        }
    }
}

// fused prep: [0,1536) x->bf16 ; [1536,1968) w_qkv^T ; [1968,2112) w_out^T
__global__ __launch_bounds__(256)
void prep_k(const float* __restrict__ x, short* __restrict__ Xb,
            const float* __restrict__ Wq, short* __restrict__ Wqt,
            const float* __restrict__ Wo, short* __restrict__ Wot)
{
    __shared__ short S[64 * 65];
    const int t = threadIdx.x;
    if (blockIdx.x < 1536) {
        int i = (blockIdx.x * 256 + t) * 8;
        float4 f0 = *(const float4*)(x + i);
        float4 f1 = *(const float4*)(x + i + 4);
        short s[8];
        s[0]=f2bf(f0.x); s[1]=f2bf(f0.y); s[2]=f2bf(f0.z); s[3]=f2bf(f0.w);
        s[4]=f2bf(f1.x); s[5]=f2bf(f1.y); s[6]=f2bf(f1.z); s[7]=f2bf(f1.w);
        *(uint4*)(Xb + i) = *(uint4*)s;
        return;
    }
    if (blockIdx.x < 1968) {
        const int b2 = blockIdx.x - 1536;                  // N=2304, K=768
        tr_tile(Wq, Wqt, 768, 2304, (b2 % 36) * 64, (b2 / 36) * 64, t, S);
    } else {
        const int b3 = blockIdx.x - 1968;                  // N=768, K=768
        tr_tile(Wo, Wot, 768, 768, (b3 % 12) * 64, (b3 / 12) * 64, t, S);
    }
}

// standalone w_out transpose (fallback when Wot must alias Wqt)
__global__ __launch_bounds__(256)
void tr_w(const float* __restrict__ W, short* __restrict__ Wt, int K, int N) {
    __shared__ short S[64 * 65];
    tr_tile(W, Wt, K, N, blockIdx.x * 64, blockIdx.y * 64, threadIdx.x, S);
}

// ---------------------------------------------------------------------------
// QKV GEMM R20: 128x96 tiles, 768 blocks = 3/CU, XCD-panel remap (R19),
// B-only LDS (3 x 6KB) + A in registers double-buffered 2 tiles ahead.
// [4096x768]bf16 @ Wqt[2304x768]^T + b -> Qb(pre-scaled)/Kb/Vt bf16
// ---------------------------------------------------------------------------
__global__ __launch_bounds__(256)
void gemm_qkv(const short* __restrict__ A, const short* __restrict__ Bt,
              const float* __restrict__ bias,
              short* __restrict__ Qb, short* __restrict__ Kb, short* __restrict__ Vt)
{
    __shared__ short Bs[3][96 * 32];   // 384 chunks per buffer (6KB)
    const int tid = threadIdx.x, lane = tid & 63, w = tid >> 6;
    const int wm = w >> 1, wn = w & 1, quad = lane >> 4, lcol = lane & 15;

    // XCD-panel-grouped remap (bijective: 768 = 8 XCD * 4 bm * 24 bn)
    const int id = blockIdx.x;
    const int xcd = id & 7, j = id >> 3;
    const int bm = (xcd * 4 + (j / 24)) * 128;
    const int bn = (j % 24) * 96;

    f32x4 acc[4][3];
    #pragma unroll
    for (int i = 0; i < 4; i++)
        #pragma unroll
        for (int jj = 0; jj < 3; jj++) acc[i][jj] = (f32x4){0.f, 0.f, 0.f, 0.f};

    const int ar0 = tid >> 2,  ac0 = (tid & 3) * 8;
    const int c2  = 256 + tid;         // only tid<128 uses it
    const int br1 = c2 >> 2,   bc1 = (c2 & 3) * 8;

    const short* pB0 = Bt + (size_t)(bn + ar0) * 768 + ac0;
    const short* pB1 = Bt + (size_t)(bn + br1) * 768 + bc1;

    // per-wave A fragment pointers (row = bm + wm*64 + tm*16 + lcol)
    const short* pA[4];
    #pragma unroll
    for (int tm = 0; tm < 4; tm++)
        pA[tm] = A + (size_t)(bm + wm*64 + tm*16 + lcol) * 768 + quad * 8;

    bf16x8 areg[2][4];
    #pragma unroll
    for (int t0 = 0; t0 < 2; t0++) {   // stage tiles 0,1 (B->LDS, A->regs)
        const int kt = t0 * 32;
        gl_lds16(pB0 + kt, Bs[t0] + tid * 8);
        if (tid < 128)
            gl_lds16(pB1 + kt, Bs[t0] + c2 * 8);
        #pragma unroll
        for (int tm = 0; tm < 4; tm++)
            areg[t0][tm] = *(const bf16x8*)(pA[tm] + kt);
    }
    if (w < 2) { WAITCNT_VM(6); } else { WAITCNT_VM(5); }   // B0+A0 landed
    BARRIER_FENCED();

    #pragma unroll
    for (int it = 0; it < 24; it++) {
        const int p = it % 3, s = it & 1;
        bf16x8 b[3];
        #pragma unroll
        for (int tn = 0; tn < 3; tn++)
            b[tn] = *(const bf16x8*)(Bs[p] + (wn*48 + tn*16 + lcol) * 32 + quad * 8);
        #pragma unroll
        for (int tm = 0; tm < 4; tm++)
            #pragma unroll
            for (int tn = 0; tn < 3; tn++)
                acc[tm][tn] = __builtin_amdgcn_mfma_f32_16x16x32_bf16(areg[s][tm], b[tn], acc[tm][tn], 0, 0, 0);
        if (it < 22) {                 // stage tile it+2: B->LDS, A->areg[s]
            const int pb = (it + 2) % 3, kt = (it + 2) * 32;
            gl_lds16(pB0 + kt, Bs[pb] + tid * 8);
            if (tid < 128)
                gl_lds16(pB1 + kt, Bs[pb] + c2 * 8);
            #pragma unroll
            for (int tm = 0; tm < 4; tm++)
                areg[s][tm] = *(const bf16x8*)(pA[tm] + kt);
        }
        if (it < 23) {
            if (it < 22) {             // drain B(it+1); keep A(it+1)+tile(it+2)
                if (w < 2) { WAITCNT_VM(10); } else { WAITCNT_VM(9); }
            } else {
                WAITCNT_VM(0);         // drain last staged tile
            }
            BARRIER_FENCED();
        }
    }

    const float SCLQ = 0.18033688011112042f;   // 0.125 * log2(e) folded into Q
    #pragma unroll
    for (int tm = 0; tm < 4; tm++) {
        #pragma unroll
        for (int tn = 0; tn < 3; tn++) {
            int col = bn + wn*48 + tn*16 + lcol;
            float bv = bias[col];
            int which = (col >= 1536) ? 2 : (col >= 768 ? 1 : 0);
            int cc = col - which * 768;
            int h = cc >> 6, d = cc & 63;
            int rowbase = bm + wm*64 + tm*16 + quad*4;
            int bb = rowbase >> 11, n0 = rowbase & 2047;
            int bh = bb * 12 + h;
            if (which == 2) {                 // V: tiled V^T store, dense window
                short4 s4;
                s4.x = f2bf(acc[tm][tn][0] + bv);
                s4.y = f2bf(acc[tm][tn][1] + bv);
                s4.z = f2bf(acc[tm][tn][2] + bv);
                s4.w = f2bf(acc[tm][tn][3] + bv);
                *(short4*)(Vt + (((size_t)bh*32 + (n0 >> 6))*64 + d)*64 + (n0 & 63)) = s4;
            } else {
                #pragma unroll
                for (int reg = 0; reg < 4; reg++) {
                    float v = acc[tm][tn][reg] + bv;
                    if (which == 0) v *= SCLQ;
                    short* dst = (which == 0) ? Qb : Kb;
                    dst[((size_t)bh*2048 + n0 + reg)*64 + d] = f2bf(v);
                }
            }
        }
    }
}

// ---------------------------------------------------------------------------
// Flash attention R20 = R18/R19 (best measured): R15 compute, compile-time
// buffer rotation via 10x3 macro-unrolled steps, 4 running DMA pointers.
// WMODE: 0 = vmcnt(4)+barrier (steady), 1 = vmcnt(0)+barrier, 2 = none.
// ---------------------------------------------------------------------------
#define ATTN_STEP(P, PB, DO_PRE, WMODE) do {                                   \
    if (DO_PRE) {                                                              \
        gl_lds16(pK0, Ks[PB] + c0 * 8);                                        \
        gl_lds16(pV0, Vs[PB] + c0 * 8);                                        \
        gl_lds16(pK1, Ks[PB] + c1 * 8);                                        \
        gl_lds16(pV1, Vs[PB] + c1 * 8);                                        \
        pK0 += 4096; pV0 += 4096; pK1 += 4096; pV1 += 4096;                    \
    }                                                                          \
    f32x4 st[4];                                                               \
    _Pragma("unroll")                                                          \
    for (int kvs = 0; kvs < 4; kvs++) st[kvs] = (f32x4){0.f, 0.f, 0.f, 0.f};   \
    _Pragma("unroll")                                                          \
    for (int ks = 0; ks < 2; ks++) {                                           \
        _Pragma("unroll")                                                      \
        for (int kvs = 0; kvs < 4; kvs++) {                                    \
            bf16x8 kf = *(const bf16x8*)(Ks[P] + (kvs*16 + lcol) * 64 +        \
                                         (((ks*4 + quad) ^ ksw) << 3));        \
            st[kvs] = __builtin_amdgcn_mfma_f32_16x16x32_bf16(kf, qf[ks],      \
                                                              st[kvs], 0, 0, 0); \
        }                                                                      \
    }                                                                          \
    uint32_t X[4], Y[4];                                                       \
    _Pragma("unroll")                                                          \
    for (int kvs = 0; kvs < 4; kvs++) {                                        \
        float p0 = exp2fast(st[kvs][0]), p1 = exp2fast(st[kvs][1]);            \
        float p2 = exp2fast(st[kvs][2]), p3 = exp2fast(st[kvs][3]);            \
        lp += (p0 + p1) + (p2 + p3);                                           \
        asm("v_cvt_pk_bf16_f32 %0, %1, %2" : "=v"(X[kvs]) : "v"(p0), "v"(p1)); \
        asm("v_cvt_pk_bf16_f32 %0, %1, %2" : "=v"(Y[kvs]) : "v"(p2), "v"(p3)); \
    }                                                                          \
    bf16x8 pa[2];                                                              \
    _Pragma("unroll")                                                          \
    for (int ks = 0; ks < 2; ks++) {                                           \
        uint32_t a0 = X[2*ks], a1 = X[2*ks + 1];                               \
        uint32_t b0 = Y[2*ks], b1 = Y[2*ks + 1];                               \
        asm("v_permlane16_swap_b32 %0, %1" : "+v"(a0), "+v"(a1));              \
        asm("v_permlane16_swap_b32 %0, %1" : "+v"(b0), "+v"(b1));              \
        union { uint32_t u[4]; bf16x8 v; } pk_;                                \
        pk_.u[0] = a0; pk_.u[1] = b0; pk_.u[2] = a1; pk_.u[3] = b1;            \
        pa[ks] = pk_.v;                                                        \
    }                                                                          \
    _Pragma("unroll")                                                          \
    for (int ks = 0; ks < 2; ks++) {                                           \
        _Pragma("unroll")                                                      \
        for (int tn = 0; tn < 4; tn++) {                                       \
            int row = tn * 16 + lcol;                                          \
            bf16x8 bv = *(const bf16x8*)(Vs[P] + row * 64 +                    \
                                         (((ks*4 + bq) ^ (row & 7)) << 3));    \
            o[tn] = __builtin_amdgcn_mfma_f32_16x16x32_bf16(pa[ks], bv,        \
                                                            o[tn], 0, 0, 0);   \
        }                                                                      \
    }                                                                          \
    if (WMODE == 0) { WAITCNT_VM(4); BARRIER_FENCED(); }                       \
    else if (WMODE == 1) { WAITCNT_VM(0); BARRIER_FENCED(); }                  \
} while (0)

__global__ __launch_bounds__(256)
void attn_k(const short* __restrict__ Q, const short* __restrict__ K,
            const short* __restrict__ Vt, short* __restrict__ Ab)
{
    __shared__ __align__(16) short Ks[3][4096];   // [kv][d] xor-swizzled chunks
    __shared__ __align__(16) short Vs[3][4096];   // [d][kv] xor-swizzled chunks

    const int tid = threadIdx.x, lane = tid & 63, w = tid >> 6;
    const int quad = lane >> 4, lcol = lane & 15;
    const int bid = blockIdx.x;
    const int bh = bid % 24, qt = bid / 24;
    const int b = bh / 12, h = bh - b * 12;

    const short* Kg = K  + (size_t)bh * 131072;   // [n][d] rows, tile = 8KB
    const short* Vg = Vt + (size_t)bh * 131072;   // tiled [kt][d][n64], 8KB

    bf16x8 qf[2];                       // this wave's 16 q rows only
    {
        const short* Qg = Q + ((size_t)bh * 2048 + (size_t)qt * 64) * 64;
        #pragma unroll
        for (int ks = 0; ks < 2; ks++)
            qf[ks] = *(const bf16x8*)(Qg + (w*16 + lcol) * 64 + ks*32 + quad*8);
    }

    // per-thread chunk mapping (c0: chunks 0..511, c1: 512..1023 of each tile)
    const int c0 = tid, c1 = tid + 256;
    const int r0 = c0 >> 3, s0 = r0 * 64 + (((c0 & 7) ^ (r0 & 7)) << 3);
    const int r1 = c1 >> 3, s1 = r1 * 64 + (((c1 & 7) ^ (r1 & 7)) << 3);

    // stage tiles 0,1 (4 loads/thread/tile, uniform)
    #pragma unroll
    for (int t0 = 0; t0 < 2; t0++) {
        gl_lds16(Kg + t0 * 4096 + s0, Ks[t0] + c0 * 8);
        gl_lds16(Vg + t0 * 4096 + s0, Vs[t0] + c0 * 8);
        gl_lds16(Kg + t0 * 4096 + s1, Ks[t0] + c1 * 8);
        gl_lds16(Vg + t0 * 4096 + s1, Vs[t0] + c1 * 8);
    }
    WAITCNT_VM(4);                     // Q loads + tile 0 landed; tile 1 in flight
    BARRIER_FENCED();

    // running prefetch source pointers (tile kt+2), advance 1 tile per step
    const short* pK0 = Kg + 2 * 4096 + s0;
    const short* pV0 = Vg + 2 * 4096 + s0;
    const short* pK1 = Kg + 2 * 4096 + s1;
    const short* pV1 = Vg + 2 * 4096 + s1;

    f32x4 o[4];
    #pragma unroll
    for (int tn = 0; tn < 4; tn++) o[tn] = (f32x4){0.f, 0.f, 0.f, 0.f};
    float lp = 0.f;

    const int ksw = lcol & 7;                       // K row-xor ((kvs*16+lcol)&7)
    const int bq  = ((quad & 1) << 1) | (quad >> 1); // V chunk bit-reverse perm

    for (int g = 0; g < 10; g++) {      // kt = 3g+0, 3g+1, 3g+2  (0..29)
        ATTN_STEP(0, 2, true, 0);
        ATTN_STEP(1, 0, true, 0);
        ATTN_STEP(2, 1, true, 0);
    }
    ATTN_STEP(0, 0, false, 1);          // kt = 30: drain tile 31
    ATTN_STEP(1, 0, false, 2);          // kt = 31: last, no barrier

    // row-sum: kv-split is across quads of the SAME wave -> pure shuffles
    lp += __shfl_xor(lp, 16, 64);
    lp += __shfl_xor(lp, 32, 64);
    float rl[4];
    #pragma unroll
    for (int r = 0; r < 4; r++)
        rl[r] = 1.0f / __shfl(lp, quad * 4 + r, 64);   // lane lcol=q' holds sum(q')

    #pragma unroll
    for (int tn = 0; tn < 4; tn++) {
        #pragma unroll
        for (int r = 0; r < 4; r++) {
            int q = qt * 64 + w * 16 + quad * 4 + r;
            int d = h * 64 + tn * 16 + lcol;
            Ab[((size_t)(b * 2048 + q)) * 768 + d] = f2bf(o[tn][r] * rl[r]);
        }
    }
}

// ---------------------------------------------------------------------------
// out-proj GEMM R20: 64x96 tiles, 512 blocks = 2/CU, XCD-panel remap (R19),
// B-only LDS (3 x 6KB) + A in registers double-buffered 2 tiles ahead.
// ---------------------------------------------------------------------------
__global__ __launch_bounds__(256)
void gemm_out(const short* __restrict__ A, const short* __restrict__ Bt,
              const float* __restrict__ bias, float* __restrict__ Of)
{
    __shared__ short Bs[3][96 * 32];   // 384 chunks per buffer (6KB)
    const int tid = threadIdx.x, lane = tid & 63, w = tid >> 6;
    const int wm = w >> 1, wn = w & 1, quad = lane >> 4, lcol = lane & 15;

    // XCD-panel-grouped remap (bijective: 512 = 8 XCD * 8 bm * 8 bn)
    const int id = blockIdx.x;
    const int xcd = id & 7, j = id >> 3;
    const int bm = (xcd * 8 + (j >> 3)) * 64;
    const int bn = (j & 7) * 96;

    f32x4 acc[2][3];
    #pragma unroll
    for (int i = 0; i < 2; i++)
        #pragma unroll
        for (int jj = 0; jj < 3; jj++) acc[i][jj] = (f32x4){0.f, 0.f, 0.f, 0.f};

    const int ar0 = tid >> 2, ac0 = (tid & 3) * 8;
    const int c2  = 256 + tid;         // only tid<128 uses it
    const int br1 = c2 >> 2,  bc1 = (c2 & 3) * 8;

    const short* pB0 = Bt + (size_t)(bn + ar0) * 768 + ac0;
    const short* pB1 = Bt + (size_t)(bn + br1) * 768 + bc1;

    const short* pA[2];
    #pragma unroll
    for (int tm = 0; tm < 2; tm++)
        pA[tm] = A + (size_t)(bm + wm*32 + tm*16 + lcol) * 768 + quad * 8;

    bf16x8 areg[2][2];
    #pragma unroll
    for (int t0 = 0; t0 < 2; t0++) {   // stage tiles 0,1
        const int kt = t0 * 32;
        gl_lds16(pB0 + kt, Bs[t0] + tid * 8);
        if (tid < 128)
            gl_lds16(pB1 + kt, Bs[t0] + c2 * 8);
        #pragma unroll
        for (int tm = 0; tm < 2; tm++)
            areg[t0][tm] = *(const bf16x8*)(pA[tm] + kt);
    }
    if (w < 2) { WAITCNT_VM(4); } else { WAITCNT_VM(3); }   // B0+A0 landed
    BARRIER_FENCED();

    #pragma unroll
    for (int it = 0; it < 24; it++) {
        const int p = it % 3, s = it & 1;
        bf16x8 b[3];
        #pragma unroll
        for (int tn = 0; tn < 3; tn++)
            b[tn] = *(const bf16x8*)(Bs[p] + (wn*48 + tn*16 + lcol) * 32 + quad * 8);
        #pragma unroll
        for (int tm = 0; tm < 2; tm++)
            #pragma unroll
            for (int tn = 0; tn < 3; tn++)
                acc[tm][tn] = __builtin_amdgcn_mfma_f32_16x16x32_bf16(areg[s][tm], b[tn], acc[tm][tn], 0, 0, 0);
        if (it < 22) {
            const int pb = (it + 2) % 3, kt = (it + 2) * 32;
            gl_lds16(pB0 + kt, Bs[pb] + tid * 8);
            if (tid < 128)
                gl_lds16(pB1 + kt, Bs[pb] + c2 * 8);
            #pragma unroll
            for (int tm = 0; tm < 2; tm++)
                areg[s][tm] = *(const bf16x8*)(pA[tm] + kt);
        }
        if (it < 23) {
            if (it < 22) {
                if (w < 2) { WAITCNT_VM(6); } else { WAITCNT_VM(5); }
            } else {
                WAITCNT_VM(0);
            }
            BARRIER_FENCED();
        }
    }
    #pragma unroll
    for (int tm = 0; tm < 2; tm++) {
        #pragma unroll
        for (int tn = 0; tn < 3; tn++) {
            int col = bn + wn*48 + tn*16 + lcol;
            float bv = bias[col];
            #pragma unroll
            for (int reg = 0; reg < 4; reg++) {
                int row = bm + wm*32 + tm*16 + quad*4 + reg;
                Of[(size_t)row * 768 + col] = acc[tm][tn][reg] + bv;
            }
        }
    }
}

// ---------------------------------------------------------------------------
extern "C" void kernel_launch(void* const* d_in, const int* in_sizes, int n_in,
                              void* d_out, int out_size, void* d_ws, size_t ws_size,
                              hipStream_t stream)
{
    (void)in_sizes; (void)n_in; (void)out_size;
    const float* x     = (const float*)d_in[0];
    const float* w_qkv = (const float*)d_in[1];
    const float* b_qkv = (const float*)d_in[2];
    const float* w_out = (const float*)d_in[3];
    const float* b_out = (const float*)d_in[4];
    float* out = (float*)d_out;

    const size_t XSZ = (size_t)4096 * 768;
    const size_t WQ  = (size_t)2304 * 768;
    const size_t WO  = (size_t)768 * 768;
    const size_t HSZ = (size_t)24 * 2048 * 64;
    short* Xb  = (short*)d_ws;
    short* Wqt = Xb + XSZ;
    short* Qb  = Wqt + WQ;
    short* Kb  = Qb + HSZ;
    short* Vt  = Kb + HSZ;
    short* Ab  = Xb;                       // x dead after gemm_qkv

    const bool sepWot = ws_size >= (XSZ + WQ + 3*HSZ + WO) * sizeof(short);
    short* Wot = sepWot ? (Vt + HSZ) : Wqt;   // else alias (w_qkv^T dead after gemm0)

    if (sepWot) {
        prep_k<<<2112, 256, 0, stream>>>(x, Xb, w_qkv, Wqt, w_out, Wot);
        gemm_qkv<<<768, 256, 0, stream>>>(Xb, Wqt, b_qkv, Qb, Kb, Vt);
    } else {
        prep_k<<<1968, 256, 0, stream>>>(x, Xb, w_qkv, Wqt, w_out, Wot);
        gemm_qkv<<<768, 256, 0, stream>>>(Xb, Wqt, b_qkv, Qb, Kb, Vt);
        tr_w<<<dim3(12, 12), 256, 0, stream>>>(w_out, Wot, 768, 768);
    }
    attn_k<<<768, 256, 0, stream>>>(Qb, Kb, Vt, Ab);
    gemm_out<<<512, 256, 0, stream>>>(Ab, Wot, b_out, out);
}

// Round 9
// 163.681 us; speedup vs baseline: 1.0477x; 1.0477x over previous
//
#include <hip/hip_runtime.h>
#include <hip/hip_bf16.h>
#include <stdint.h>

// Attention fwd: B=2, N=2048, D=768, H=12, Dh=64, INNER=768
// R21 = R19 (attn_k/prep_k/gemm_out byte-identical; R20's A-in-regs REVERTED
// -- it regressed, gemm_qkv 46us with per-lane A loads uncoalesced) +
// gemm_qkv re-tiled for TLP: R20 counters showed latency-bound lockstep
// (MfmaUtil 12%, VALU 9%, HBM 5%, ~4600cy/round vs ~1100cy work) at only
// 3 blocks/CU. New: 64x96 tiles, grid 1536 = 6 blocks/CU, 2-buffer drain-0
// (R13-proven structure), LDS 20KB, XCD panel remap re-derived
// (1536 = 8 xcd x 8 bm x 24 bn; per-XCD A 0.77MB + B 3.5MB, L2-resident).

typedef __attribute__((ext_vector_type(8))) short bf16x8;
typedef __attribute__((ext_vector_type(4))) float f32x4;
typedef __attribute__((address_space(3))) unsigned int lds_uint;
typedef __attribute__((address_space(1))) const unsigned int g_uint;

__device__ __forceinline__ short f2bf(float f) {
    union { float f; uint32_t u; } x; x.f = f;
    uint32_t r = (x.u + 0x7fffu + ((x.u >> 16) & 1u)) >> 16;
    return (short)r;
}
__device__ __forceinline__ float exp2fast(float x) {
#if __has_builtin(__builtin_amdgcn_exp2f)
    return __builtin_amdgcn_exp2f(x);
#else
    return __expf(x * 0.6931471805599453f);
#endif
}
__device__ __forceinline__ void gl_lds16(const void* g, void* l) {
    __builtin_amdgcn_global_load_lds((g_uint*)g, (lds_uint*)l, 16, 0, 0);
}
#define WAITCNT_VM(N) asm volatile("s_waitcnt vmcnt(" #N ")" ::: "memory")
#define BARRIER_FENCED() do { __builtin_amdgcn_s_barrier(); \
                              asm volatile("" ::: "memory"); } while (0)

// ---------------------------------------------------------------------------
// 64x64 fp32->bf16 transpose tile (shared by prep_k / tr_w)
// ---------------------------------------------------------------------------
__device__ __forceinline__ void tr_tile(const float* __restrict__ W,
                                        short* __restrict__ Wt, int K, int N,
                                        int n0, int k0, int t, short* S) {
    {
        int kl = t >> 2, ng = t & 3;
        const float* src = W + (size_t)(k0 + kl) * N + n0 + ng * 16;
        #pragma unroll
        for (int j = 0; j < 16; j += 4) {
            float4 f = *(const float4*)(src + j);
            S[(ng*16 + j + 0) * 65 + kl] = f2bf(f.x);
            S[(ng*16 + j + 1) * 65 + kl] = f2bf(f.y);
            S[(ng*16 + j + 2) * 65 + kl] = f2bf(f.z);
            S[(ng*16 + j + 3) * 65 + kl] = f2bf(f.w);
        }
    }
    __syncthreads();
    {
        int nl = t >> 2, kg = t & 3;
        short* dst = Wt + (size_t)(n0 + nl) * K + k0 + kg * 16;
        #pragma unroll
        for (int j = 0; j < 16; j += 4) {
            short4 s4;
            s4.x = S[nl*65 + kg*16 + j + 0];
            s4.y = S[nl*65 + kg*16 + j + 1];
            s4.z = S[nl*65 + kg*16 + j + 2];
            s4.w = S[nl*65 + kg*16 + j + 3];
            *(short4*)(dst + j) = s4;
        }
    }
}

// fused prep: [0,1536) x->bf16 ; [1536,1968) w_qkv^T ; [1968,2112) w_out^T
__global__ __launch_bounds__(256)
void prep_k(const float* __restrict__ x, short* __restrict__ Xb,
            const float* __restrict__ Wq, short* __restrict__ Wqt,
            const float* __restrict__ Wo, short* __restrict__ Wot)
{
    __shared__ short S[64 * 65];
    const int t = threadIdx.x;
    if (blockIdx.x < 1536) {
        int i = (blockIdx.x * 256 + t) * 8;
        float4 f0 = *(const float4*)(x + i);
        float4 f1 = *(const float4*)(x + i + 4);
        short s[8];
        s[0]=f2bf(f0.x); s[1]=f2bf(f0.y); s[2]=f2bf(f0.z); s[3]=f2bf(f0.w);
        s[4]=f2bf(f1.x); s[5]=f2bf(f1.y); s[6]=f2bf(f1.z); s[7]=f2bf(f1.w);
        *(uint4*)(Xb + i) = *(uint4*)s;
        return;
    }
    if (blockIdx.x < 1968) {
        const int b2 = blockIdx.x - 1536;                  // N=2304, K=768
        tr_tile(Wq, Wqt, 768, 2304, (b2 % 36) * 64, (b2 / 36) * 64, t, S);
    } else {
        const int b3 = blockIdx.x - 1968;                  // N=768, K=768
        tr_tile(Wo, Wot, 768, 768, (b3 % 12) * 64, (b3 / 12) * 64, t, S);
    }
}

// standalone w_out transpose (fallback when Wot must alias Wqt)
__global__ __launch_bounds__(256)
void tr_w(const float* __restrict__ W, short* __restrict__ Wt, int K, int N) {
    __shared__ short S[64 * 65];
    tr_tile(W, Wt, K, N, blockIdx.x * 64, blockIdx.y * 64, threadIdx.x, S);
}

// ---------------------------------------------------------------------------
// QKV GEMM R21: 64x96 tiles, 1536 blocks = 6/CU (TLP), 2-buffer drain-0
// (R13-proven), gl_lds16 staging, fully unrolled, XCD panel remap.
// [4096x768]bf16 @ Wqt[2304x768]^T + b -> Qb(pre-scaled)/Kb/Vt bf16
// Vt layout TILED: Vt[bh][kt][d][n&63] (64x64 tiles, 8KB, dense windows)
// ---------------------------------------------------------------------------
__global__ __launch_bounds__(256)
void gemm_qkv(const short* __restrict__ A, const short* __restrict__ Bt,
              const float* __restrict__ bias,
              short* __restrict__ Qb, short* __restrict__ Kb, short* __restrict__ Vt)
{
    __shared__ short As[2][64 * 32];   // 256 chunks per buffer (4KB)
    __shared__ short Bs[2][96 * 32];   // 384 chunks per buffer (6KB)
    const int tid = threadIdx.x, lane = tid & 63, w = tid >> 6;
    const int wm = w >> 1, wn = w & 1, quad = lane >> 4, lcol = lane & 15;

    // XCD-panel-grouped remap (bijective: 1536 = 8 XCD * 8 bm * 24 bn)
    const int id = blockIdx.x;
    const int xcd = id & 7, j = id >> 3;
    const int bm = (xcd * 8 + (j / 24)) * 64;
    const int bn = (j % 24) * 96;

    f32x4 acc[2][3];
    #pragma unroll
    for (int i = 0; i < 2; i++)
        #pragma unroll
        for (int jj = 0; jj < 3; jj++) acc[i][jj] = (f32x4){0.f, 0.f, 0.f, 0.f};

    const int ar0 = tid >> 2, ac0 = (tid & 3) * 8;
    const int c2  = 256 + tid;         // only tid<128 uses it
    const int br1 = c2 >> 2,  bc1 = (c2 & 3) * 8;

    const short* pA0 = A  + (size_t)(bm + ar0) * 768 + ac0;
    const short* pB0 = Bt + (size_t)(bn + ar0) * 768 + ac0;
    const short* pB1 = Bt + (size_t)(bn + br1) * 768 + bc1;

    // stage tile 0 into buffer 0
    gl_lds16(pA0, As[0] + tid * 8);
    gl_lds16(pB0, Bs[0] + tid * 8);
    if (tid < 128)
        gl_lds16(pB1, Bs[0] + c2 * 8);
    __syncthreads();

    #pragma unroll
    for (int it = 0; it < 24; it++) {
        const int p = it & 1;
        if (it < 23) {                 // prefetch next k-tile into alt buffer
            const int kt = (it + 1) * 32;
            gl_lds16(pA0 + kt, As[p ^ 1] + tid * 8);
            gl_lds16(pB0 + kt, Bs[p ^ 1] + tid * 8);
            if (tid < 128)
                gl_lds16(pB1 + kt, Bs[p ^ 1] + c2 * 8);
        }
        bf16x8 a[2], b[3];
        #pragma unroll
        for (int tm = 0; tm < 2; tm++)
            a[tm] = *(const bf16x8*)(As[p] + (wm*32 + tm*16 + lcol) * 32 + quad * 8);
        #pragma unroll
        for (int tn = 0; tn < 3; tn++)
            b[tn] = *(const bf16x8*)(Bs[p] + (wn*48 + tn*16 + lcol) * 32 + quad * 8);
        #pragma unroll
        for (int tm = 0; tm < 2; tm++)
            #pragma unroll
            for (int tn = 0; tn < 3; tn++)
                acc[tm][tn] = __builtin_amdgcn_mfma_f32_16x16x32_bf16(a[tm], b[tn], acc[tm][tn], 0, 0, 0);
        __syncthreads();               // drains prefetch DMA + guards buffer swap
    }

    const float SCLQ = 0.18033688011112042f;   // 0.125 * log2(e) folded into Q
    #pragma unroll
    for (int tm = 0; tm < 2; tm++) {
        #pragma unroll
        for (int tn = 0; tn < 3; tn++) {
            int col = bn + wn*48 + tn*16 + lcol;
            float bv = bias[col];
            int which = (col >= 1536) ? 2 : (col >= 768 ? 1 : 0);
            int cc = col - which * 768;
            int h = cc >> 6, d = cc & 63;
            int rowbase = bm + wm*32 + tm*16 + quad*4;
            int bb = rowbase >> 11, n0 = rowbase & 2047;
            int bh = bb * 12 + h;
            if (which == 2) {                 // V: tiled V^T store, dense window
                short4 s4;
                s4.x = f2bf(acc[tm][tn][0] + bv);
                s4.y = f2bf(acc[tm][tn][1] + bv);
                s4.z = f2bf(acc[tm][tn][2] + bv);
                s4.w = f2bf(acc[tm][tn][3] + bv);
                *(short4*)(Vt + (((size_t)bh*32 + (n0 >> 6))*64 + d)*64 + (n0 & 63)) = s4;
            } else {
                #pragma unroll
                for (int reg = 0; reg < 4; reg++) {
                    float v = acc[tm][tn][reg] + bv;
                    if (which == 0) v *= SCLQ;
                    short* dst = (which == 0) ? Qb : Kb;
                    dst[((size_t)bh*2048 + n0 + reg)*64 + d] = f2bf(v);
                }
            }
        }
    }
}

// ---------------------------------------------------------------------------
// Flash attention R21 = R19 (best measured): R15 compute, compile-time
// buffer rotation via 10x3 macro-unrolled steps, 4 running DMA pointers.
// WMODE: 0 = vmcnt(4)+barrier (steady), 1 = vmcnt(0)+barrier, 2 = none.
// ---------------------------------------------------------------------------
#define ATTN_STEP(P, PB, DO_PRE, WMODE) do {                                   \
    if (DO_PRE) {                                                              \
        gl_lds16(pK0, Ks[PB] + c0 * 8);                                        \
        gl_lds16(pV0, Vs[PB] + c0 * 8);                                        \
        gl_lds16(pK1, Ks[PB] + c1 * 8);                                        \
        gl_lds16(pV1, Vs[PB] + c1 * 8);                                        \
        pK0 += 4096; pV0 += 4096; pK1 += 4096; pV1 += 4096;                    \
    }                                                                          \
    f32x4 st[4];                                                               \
    _Pragma("unroll")                                                          \
    for (int kvs = 0; kvs < 4; kvs++) st[kvs] = (f32x4){0.f, 0.f, 0.f, 0.f};   \
    _Pragma("unroll")                                                          \
    for (int ks = 0; ks < 2; ks++) {                                           \
        _Pragma("unroll")                                                      \
        for (int kvs = 0; kvs < 4; kvs++) {                                    \
            bf16x8 kf = *(const bf16x8*)(Ks[P] + (kvs*16 + lcol) * 64 +        \
                                         (((ks*4 + quad) ^ ksw) << 3));        \
            st[kvs] = __builtin_amdgcn_mfma_f32_16x16x32_bf16(kf, qf[ks],      \
                                                              st[kvs], 0, 0, 0); \
        }                                                                      \
    }                                                                          \
    uint32_t X[4], Y[4];                                                       \
    _Pragma("unroll")                                                          \
    for (int kvs = 0; kvs < 4; kvs++) {                                        \
        float p0 = exp2fast(st[kvs][0]), p1 = exp2fast(st[kvs][1]);            \
        float p2 = exp2fast(st[kvs][2]), p3 = exp2fast(st[kvs][3]);            \
        lp += (p0 + p1) + (p2 + p3);                                           \
        asm("v_cvt_pk_bf16_f32 %0, %1, %2" : "=v"(X[kvs]) : "v"(p0), "v"(p1)); \
        asm("v_cvt_pk_bf16_f32 %0, %1, %2" : "=v"(Y[kvs]) : "v"(p2), "v"(p3)); \
    }                                                                          \
    bf16x8 pa[2];                                                              \
    _Pragma("unroll")                                                          \
    for (int ks = 0; ks < 2; ks++) {                                           \
        uint32_t a0 = X[2*ks], a1 = X[2*ks + 1];                               \
        uint32_t b0 = Y[2*ks], b1 = Y[2*ks + 1];                               \
        asm("v_permlane16_swap_b32 %0, %1" : "+v"(a0), "+v"(a1));              \
        asm("v_permlane16_swap_b32 %0, %1" : "+v"(b0), "+v"(b1));              \
        union { uint32_t u[4]; bf16x8 v; } pk_;                                \
        pk_.u[0] = a0; pk_.u[1] = b0; pk_.u[2] = a1; pk_.u[3] = b1;            \
        pa[ks] = pk_.v;                                                        \
    }                                                                          \
    _Pragma("unroll")                                                          \
    for (int ks = 0; ks < 2; ks++) {                                           \
        _Pragma("unroll")                                                      \
        for (int tn = 0; tn < 4; tn++) {                                       \
            int row = tn * 16 + lcol;                                          \
            bf16x8 bv = *(const bf16x8*)(Vs[P] + row * 64 +                    \
                                         (((ks*4 + bq) ^ (row & 7)) << 3));    \
            o[tn] = __builtin_amdgcn_mfma_f32_16x16x32_bf16(pa[ks], bv,        \
                                                            o[tn], 0, 0, 0);   \
        }                                                                      \
    }                                                                          \
    if (WMODE == 0) { WAITCNT_VM(4); BARRIER_FENCED(); }                       \
    else if (WMODE == 1) { WAITCNT_VM(0); BARRIER_FENCED(); }                  \
} while (0)

__global__ __launch_bounds__(256)
void attn_k(const short* __restrict__ Q, const short* __restrict__ K,
            const short* __restrict__ Vt, short* __restrict__ Ab)
{
    __shared__ __align__(16) short Ks[3][4096];   // [kv][d] xor-swizzled chunks
    __shared__ __align__(16) short Vs[3][4096];   // [d][kv] xor-swizzled chunks

    const int tid = threadIdx.x, lane = tid & 63, w = tid >> 6;
    const int quad = lane >> 4, lcol = lane & 15;
    const int bid = blockIdx.x;
    const int bh = bid % 24, qt = bid / 24;
    const int b = bh / 12, h = bh - b * 12;

    const short* Kg = K  + (size_t)bh * 131072;   // [n][d] rows, tile = 8KB
    const short* Vg = Vt + (size_t)bh * 131072;   // tiled [kt][d][n64], 8KB

    bf16x8 qf[2];                       // this wave's 16 q rows only
    {
        const short* Qg = Q + ((size_t)bh * 2048 + (size_t)qt * 64) * 64;
        #pragma unroll
        for (int ks = 0; ks < 2; ks++)
            qf[ks] = *(const bf16x8*)(Qg + (w*16 + lcol) * 64 + ks*32 + quad*8);
    }

    // per-thread chunk mapping (c0: chunks 0..511, c1: 512..1023 of each tile)
    const int c0 = tid, c1 = tid + 256;
    const int r0 = c0 >> 3, s0 = r0 * 64 + (((c0 & 7) ^ (r0 & 7)) << 3);
    const int r1 = c1 >> 3, s1 = r1 * 64 + (((c1 & 7) ^ (r1 & 7)) << 3);

    // stage tiles 0,1 (4 loads/thread/tile, uniform)
    #pragma unroll
    for (int t0 = 0; t0 < 2; t0++) {
        gl_lds16(Kg + t0 * 4096 + s0, Ks[t0] + c0 * 8);
        gl_lds16(Vg + t0 * 4096 + s0, Vs[t0] + c0 * 8);
        gl_lds16(Kg + t0 * 4096 + s1, Ks[t0] + c1 * 8);
        gl_lds16(Vg + t0 * 4096 + s1, Vs[t0] + c1 * 8);
    }
    WAITCNT_VM(4);                     // Q loads + tile 0 landed; tile 1 in flight
    BARRIER_FENCED();

    // running prefetch source pointers (tile kt+2), advance 1 tile per step
    const short* pK0 = Kg + 2 * 4096 + s0;
    const short* pV0 = Vg + 2 * 4096 + s0;
    const short* pK1 = Kg + 2 * 4096 + s1;
    const short* pV1 = Vg + 2 * 4096 + s1;

    f32x4 o[4];
    #pragma unroll
    for (int tn = 0; tn < 4; tn++) o[tn] = (f32x4){0.f, 0.f, 0.f, 0.f};
    float lp = 0.f;

    const int ksw = lcol & 7;                       // K row-xor ((kvs*16+lcol)&7)
    const int bq  = ((quad & 1) << 1) | (quad >> 1); // V chunk bit-reverse perm

    for (int g = 0; g < 10; g++) {      // kt = 3g+0, 3g+1, 3g+2  (0..29)
        ATTN_STEP(0, 2, true, 0);
        ATTN_STEP(1, 0, true, 0);
        ATTN_STEP(2, 1, true, 0);
    }
    ATTN_STEP(0, 0, false, 1);          // kt = 30: drain tile 31
    ATTN_STEP(1, 0, false, 2);          // kt = 31: last, no barrier

    // row-sum: kv-split is across quads of the SAME wave -> pure shuffles
    lp += __shfl_xor(lp, 16, 64);
    lp += __shfl_xor(lp, 32, 64);
    float rl[4];
    #pragma unroll
    for (int r = 0; r < 4; r++)
        rl[r] = 1.0f / __shfl(lp, quad * 4 + r, 64);   // lane lcol=q' holds sum(q')

    #pragma unroll
    for (int tn = 0; tn < 4; tn++) {
        #pragma unroll
        for (int r = 0; r < 4; r++) {
            int q = qt * 64 + w * 16 + quad * 4 + r;
            int d = h * 64 + tn * 16 + lcol;
            Ab[((size_t)(b * 2048 + q)) * 768 + d] = f2bf(o[tn][r] * rl[r]);
        }
    }
}

// ---------------------------------------------------------------------------
// out-proj GEMM R21 = R19: 64x96 tiles, 512 blocks = 2/CU, triple-buffered
// counted vmcnt, fully unrolled, XCD panel remap (8 x 8 bm x 8 bn).
// ---------------------------------------------------------------------------
__global__ __launch_bounds__(256)
void gemm_out(const short* __restrict__ A, const short* __restrict__ Bt,
              const float* __restrict__ bias, float* __restrict__ Of)
{
    __shared__ short As[3][64 * 32];   // 256 chunks per buffer (12KB)
    __shared__ short Bs[3][96 * 32];   // 384 chunks per buffer (18KB)
    const int tid = threadIdx.x, lane = tid & 63, w = tid >> 6;
    const int wm = w >> 1, wn = w & 1, quad = lane >> 4, lcol = lane & 15;

    // XCD-panel-grouped remap (bijective: 512 = 8 XCD * 8 bm * 8 bn)
    const int id = blockIdx.x;
    const int xcd = id & 7, j = id >> 3;
    const int bm = (xcd * 8 + (j >> 3)) * 64;
    const int bn = (j & 7) * 96;

    f32x4 acc[2][3];
    #pragma unroll
    for (int i = 0; i < 2; i++)
        #pragma unroll
        for (int jj = 0; jj < 3; jj++) acc[i][jj] = (f32x4){0.f, 0.f, 0.f, 0.f};

    const int ar0 = tid >> 2, ac0 = (tid & 3) * 8;
    const int c2  = 256 + tid;         // only tid<128 uses it
    const int br1 = c2 >> 2,  bc1 = (c2 & 3) * 8;

    const short* pA0 = A  + (size_t)(bm + ar0) * 768 + ac0;
    const short* pB0 = Bt + (size_t)(bn + ar0) * 768 + ac0;
    const short* pB1 = Bt + (size_t)(bn + br1) * 768 + bc1;

    #pragma unroll
    for (int t0 = 0; t0 < 2; t0++) {   // stage tiles 0,1
        const int kt = t0 * 32;
        gl_lds16(pA0 + kt, As[t0] + tid * 8);
        gl_lds16(pB0 + kt, Bs[t0] + tid * 8);
        if (tid < 128)
            gl_lds16(pB1 + kt, Bs[t0] + c2 * 8);
    }
    if (w < 2) { WAITCNT_VM(3); } else { WAITCNT_VM(2); }
    BARRIER_FENCED();

    #pragma unroll
    for (int it = 0; it < 24; it++) {
        const int p = it % 3;
        if (it < 22) {
            const int pb = (it + 2) % 3, kt = (it + 2) * 32;
            gl_lds16(pA0 + kt, As[pb] + tid * 8);
            gl_lds16(pB0 + kt, Bs[pb] + tid * 8);
            if (tid < 128)
                gl_lds16(pB1 + kt, Bs[pb] + c2 * 8);
        }
        bf16x8 a[2], b[3];
        #pragma unroll
        for (int tm = 0; tm < 2; tm++)
            a[tm] = *(const bf16x8*)(As[p] + (wm*32 + tm*16 + lcol) * 32 + quad * 8);
        #pragma unroll
        for (int tn = 0; tn < 3; tn++)
            b[tn] = *(const bf16x8*)(Bs[p] + (wn*48 + tn*16 + lcol) * 32 + quad * 8);
        #pragma unroll
        for (int tm = 0; tm < 2; tm++)
            #pragma unroll
            for (int tn = 0; tn < 3; tn++)
                acc[tm][tn] = __builtin_amdgcn_mfma_f32_16x16x32_bf16(a[tm], b[tn], acc[tm][tn], 0, 0, 0);
        if (it < 23) {
            if (it < 22) {
                if (w < 2) { WAITCNT_VM(3); } else { WAITCNT_VM(2); }
            } else {
                WAITCNT_VM(0);
            }
            BARRIER_FENCED();
        }
    }
    #pragma unroll
    for (int tm = 0; tm < 2; tm++) {
        #pragma unroll
        for (int tn = 0; tn < 3; tn++) {
            int col = bn + wn*48 + tn*16 + lcol;
            float bv = bias[col];
            #pragma unroll
            for (int reg = 0; reg < 4; reg++) {
                int row = bm + wm*32 + tm*16 + quad*4 + reg;
                Of[(size_t)row * 768 + col] = acc[tm][tn][reg] + bv;
            }
        }
    }
}

// ---------------------------------------------------------------------------
extern "C" void kernel_launch(void* const* d_in, const int* in_sizes, int n_in,
                              void* d_out, int out_size, void* d_ws, size_t ws_size,
                              hipStream_t stream)
{
    (void)in_sizes; (void)n_in; (void)out_size;
    const float* x     = (const float*)d_in[0];
    const float* w_qkv = (const float*)d_in[1];
    const float* b_qkv = (const float*)d_in[2];
    const float* w_out = (const float*)d_in[3];
    const float* b_out = (const float*)d_in[4];
    float* out = (float*)d_out;

    const size_t XSZ = (size_t)4096 * 768;
    const size_t WQ  = (size_t)2304 * 768;
    const size_t WO  = (size_t)768 * 768;
    const size_t HSZ = (size_t)24 * 2048 * 64;
    short* Xb  = (short*)d_ws;
    short* Wqt = Xb + XSZ;
    short* Qb  = Wqt + WQ;
    short* Kb  = Qb + HSZ;
    short* Vt  = Kb + HSZ;
    short* Ab  = Xb;                       // x dead after gemm_qkv

    const bool sepWot = ws_size >= (XSZ + WQ + 3*HSZ + WO) * sizeof(short);
    short* Wot = sepWot ? (Vt + HSZ) : Wqt;   // else alias (w_qkv^T dead after gemm0)

    if (sepWot) {
        prep_k<<<2112, 256, 0, stream>>>(x, Xb, w_qkv, Wqt, w_out, Wot);
        gemm_qkv<<<1536, 256, 0, stream>>>(Xb, Wqt, b_qkv, Qb, Kb, Vt);
    } else {
        prep_k<<<1968, 256, 0, stream>>>(x, Xb, w_qkv, Wqt, w_out, Wot);
        gemm_qkv<<<1536, 256, 0, stream>>>(Xb, Wqt, b_qkv, Qb, Kb, Vt);
        tr_w<<<dim3(12, 12), 256, 0, stream>>>(w_out, Wot, 768, 768);
    }
    attn_k<<<768, 256, 0, stream>>>(Qb, Kb, Vt, Ab);
    gemm_out<<<512, 256, 0, stream>>>(Ab, Wot, b_out, out);
}

// Round 10
// 150.690 us; speedup vs baseline: 1.1381x; 1.0862x over previous
//
#include <hip/hip_runtime.h>
#include <hip/hip_bf16.h>
#include <stdint.h>

// Attention fwd: B=2, N=2048, D=768, H=12, Dh=64, INNER=768
// R22 = exact R19 (measured best 152.3us: attn_k/prep_k/gemm_qkv byte-
// identical; R20 A-in-regs and R21 retile both REVERTED -- each lost ~11-19us
// to R19's 128x96 triple-buffer counted-vmcnt qkv) + ONE change:
// gemm_out (grid-capped 2 blocks/CU = 8 waves, worst TLP, LDS nearly free)
// goes 5-BUFFER / DISTANCE-3 / BARRIER-EVERY-2-ROUNDS with counted vmcnt.
// Hazard audit: issue@it overwrites buffer read@it-2; barriers end-of-odd
// rounds cover exactly those reads; vmcnt(L) leaves only current round's
// loads in flight so reads@it+1/it+2 (tiles issued @it-2/it-1) are landed.
// Barriers 24->12, prefetch cover 1->3 rounds, LDS 30->50KB (still 2/CU).

typedef __attribute__((ext_vector_type(8))) short bf16x8;
typedef __attribute__((ext_vector_type(4))) float f32x4;
typedef __attribute__((address_space(3))) unsigned int lds_uint;
typedef __attribute__((address_space(1))) const unsigned int g_uint;

__device__ __forceinline__ short f2bf(float f) {
    union { float f; uint32_t u; } x; x.f = f;
    uint32_t r = (x.u + 0x7fffu + ((x.u >> 16) & 1u)) >> 16;
    return (short)r;
}
__device__ __forceinline__ float exp2fast(float x) {
#if __has_builtin(__builtin_amdgcn_exp2f)
    return __builtin_amdgcn_exp2f(x);
#else
    return __expf(x * 0.6931471805599453f);
#endif
}
__device__ __forceinline__ void gl_lds16(const void* g, void* l) {
    __builtin_amdgcn_global_load_lds((g_uint*)g, (lds_uint*)l, 16, 0, 0);
}
#define WAITCNT_VM(N) asm volatile("s_waitcnt vmcnt(" #N ")" ::: "memory")
#define BARRIER_FENCED() do { __builtin_amdgcn_s_barrier(); \
                              asm volatile("" ::: "memory"); } while (0)

// ---------------------------------------------------------------------------
// 64x64 fp32->bf16 transpose tile (shared by prep_k / tr_w)
// ---------------------------------------------------------------------------
__device__ __forceinline__ void tr_tile(const float* __restrict__ W,
                                        short* __restrict__ Wt, int K, int N,
                                        int n0, int k0, int t, short* S) {
    {
        int kl = t >> 2, ng = t & 3;
        const float* src = W + (size_t)(k0 + kl) * N + n0 + ng * 16;
        #pragma unroll
        for (int j = 0; j < 16; j += 4) {
            float4 f = *(const float4*)(src + j);
            S[(ng*16 + j + 0) * 65 + kl] = f2bf(f.x);
            S[(ng*16 + j + 1) * 65 + kl] = f2bf(f.y);
            S[(ng*16 + j + 2) * 65 + kl] = f2bf(f.z);
            S[(ng*16 + j + 3) * 65 + kl] = f2bf(f.w);
        }
    }
    __syncthreads();
    {
        int nl = t >> 2, kg = t & 3;
        short* dst = Wt + (size_t)(n0 + nl) * K + k0 + kg * 16;
        #pragma unroll
        for (int j = 0; j < 16; j += 4) {
            short4 s4;
            s4.x = S[nl*65 + kg*16 + j + 0];
            s4.y = S[nl*65 + kg*16 + j + 1];
            s4.z = S[nl*65 + kg*16 + j + 2];
            s4.w = S[nl*65 + kg*16 + j + 3];
            *(short4*)(dst + j) = s4;
        }
    }
}

// fused prep: [0,1536) x->bf16 ; [1536,1968) w_qkv^T ; [1968,2112) w_out^T
__global__ __launch_bounds__(256)
void prep_k(const float* __restrict__ x, short* __restrict__ Xb,
            const float* __restrict__ Wq, short* __restrict__ Wqt,
            const float* __restrict__ Wo, short* __restrict__ Wot)
{
    __shared__ short S[64 * 65];
    const int t = threadIdx.x;
    if (blockIdx.x < 1536) {
        int i = (blockIdx.x * 256 + t) * 8;
        float4 f0 = *(const float4*)(x + i);
        float4 f1 = *(const float4*)(x + i + 4);
        short s[8];
        s[0]=f2bf(f0.x); s[1]=f2bf(f0.y); s[2]=f2bf(f0.z); s[3]=f2bf(f0.w);
        s[4]=f2bf(f1.x); s[5]=f2bf(f1.y); s[6]=f2bf(f1.z); s[7]=f2bf(f1.w);
        *(uint4*)(Xb + i) = *(uint4*)s;
        return;
    }
    if (blockIdx.x < 1968) {
        const int b2 = blockIdx.x - 1536;                  // N=2304, K=768
        tr_tile(Wq, Wqt, 768, 2304, (b2 % 36) * 64, (b2 / 36) * 64, t, S);
    } else {
        const int b3 = blockIdx.x - 1968;                  // N=768, K=768
        tr_tile(Wo, Wot, 768, 768, (b3 % 12) * 64, (b3 / 12) * 64, t, S);
    }
}

// standalone w_out transpose (fallback when Wot must alias Wqt)
__global__ __launch_bounds__(256)
void tr_w(const float* __restrict__ W, short* __restrict__ Wt, int K, int N) {
    __shared__ short S[64 * 65];
    tr_tile(W, Wt, K, N, blockIdx.x * 64, blockIdx.y * 64, threadIdx.x, S);
}

// ---------------------------------------------------------------------------
// QKV GEMM R22 = R19: 128x96 tiles, 768 blocks = 3/CU, triple-buffered
// counted-vmcnt staging, fully unrolled K-loop, XCD panel remap
// (768 = 8 xcd x 4 bm x 24 bn; per-XCD A 0.77MB + B 3.5MB, L2-resident).
// [4096x768]bf16 @ Wqt[2304x768]^T + b -> Qb(pre-scaled)/Kb/Vt bf16
// ---------------------------------------------------------------------------
__global__ __launch_bounds__(256)
void gemm_qkv(const short* __restrict__ A, const short* __restrict__ Bt,
              const float* __restrict__ bias,
              short* __restrict__ Qb, short* __restrict__ Kb, short* __restrict__ Vt)
{
    __shared__ short As[3][128 * 32];  // 512 chunks of 16B per buffer (24KB)
    __shared__ short Bs[3][96 * 32];   // 384 chunks per buffer (18KB)
    const int tid = threadIdx.x, lane = tid & 63, w = tid >> 6;
    const int wm = w >> 1, wn = w & 1, quad = lane >> 4, lcol = lane & 15;

    // XCD-panel-grouped remap (bijective: 768 = 8 XCD * 4 bm * 24 bn)
    const int id = blockIdx.x;
    const int xcd = id & 7, j = id >> 3;
    const int bm = (xcd * 4 + (j / 24)) * 128;
    const int bn = (j % 24) * 96;

    f32x4 acc[4][3];
    #pragma unroll
    for (int i = 0; i < 4; i++)
        #pragma unroll
        for (int jj = 0; jj < 3; jj++) acc[i][jj] = (f32x4){0.f, 0.f, 0.f, 0.f};

    const int ar0 = tid >> 2,         ac0 = (tid & 3) * 8;
    const int ar1 = (tid + 256) >> 2;
    const int c2  = 256 + tid;         // only tid<128 uses it
    const int br1 = c2 >> 2,          bc1 = (c2 & 3) * 8;

    const short* pA0 = A  + (size_t)(bm + ar0) * 768 + ac0;
    const short* pA1 = A  + (size_t)(bm + ar1) * 768 + ac0;
    const short* pB0 = Bt + (size_t)(bn + ar0) * 768 + ac0;
    const short* pB1 = Bt + (size_t)(bn + br1) * 768 + bc1;

    #pragma unroll
    for (int t0 = 0; t0 < 2; t0++) {   // stage tiles 0,1
        const int kt = t0 * 32;
        gl_lds16(pA0 + kt, As[t0] + tid * 8);
        gl_lds16(pA1 + kt, As[t0] + (tid + 256) * 8);
        gl_lds16(pB0 + kt, Bs[t0] + tid * 8);
        if (tid < 128)
            gl_lds16(pB1 + kt, Bs[t0] + c2 * 8);
    }
    if (w < 2) { WAITCNT_VM(4); } else { WAITCNT_VM(3); }   // tile0 done, tile1 in flight
    BARRIER_FENCED();

    #pragma unroll
    for (int it = 0; it < 24; it++) {
        const int p = it % 3;
        if (it < 22) {                 // prefetch tile it+2 (constants after unroll)
            const int pb = (it + 2) % 3, kt = (it + 2) * 32;
            gl_lds16(pA0 + kt, As[pb] + tid * 8);
            gl_lds16(pA1 + kt, As[pb] + (tid + 256) * 8);
            gl_lds16(pB0 + kt, Bs[pb] + tid * 8);
            if (tid < 128)
                gl_lds16(pB1 + kt, Bs[pb] + c2 * 8);
        }
        bf16x8 a[4], b[3];
        #pragma unroll
        for (int tm = 0; tm < 4; tm++)
            a[tm] = *(const bf16x8*)(As[p] + (wm*64 + tm*16 + lcol) * 32 + quad * 8);
        #pragma unroll
        for (int tn = 0; tn < 3; tn++)
            b[tn] = *(const bf16x8*)(Bs[p] + (wn*48 + tn*16 + lcol) * 32 + quad * 8);
        #pragma unroll
        for (int tm = 0; tm < 4; tm++)
            #pragma unroll
            for (int tn = 0; tn < 3; tn++)
                acc[tm][tn] = __builtin_amdgcn_mfma_f32_16x16x32_bf16(a[tm], b[tn], acc[tm][tn], 0, 0, 0);
        if (it < 23) {
            if (it < 22) {             // tile it+1 landed, it+2 stays in flight
                if (w < 2) { WAITCNT_VM(4); } else { WAITCNT_VM(3); }
            } else {
                WAITCNT_VM(0);         // drain last staged tile
            }
            BARRIER_FENCED();
        }
    }

    const float SCLQ = 0.18033688011112042f;   // 0.125 * log2(e) folded into Q
    #pragma unroll
    for (int tm = 0; tm < 4; tm++) {
        #pragma unroll
        for (int tn = 0; tn < 3; tn++) {
            int col = bn + wn*48 + tn*16 + lcol;
            float bv = bias[col];
            int which = (col >= 1536) ? 2 : (col >= 768 ? 1 : 0);
            int cc = col - which * 768;
            int h = cc >> 6, d = cc & 63;
            int rowbase = bm + wm*64 + tm*16 + quad*4;
            int bb = rowbase >> 11, n0 = rowbase & 2047;
            int bh = bb * 12 + h;
            if (which == 2) {                 // V: tiled V^T store, dense window
                short4 s4;
                s4.x = f2bf(acc[tm][tn][0] + bv);
                s4.y = f2bf(acc[tm][tn][1] + bv);
                s4.z = f2bf(acc[tm][tn][2] + bv);
                s4.w = f2bf(acc[tm][tn][3] + bv);
                *(short4*)(Vt + (((size_t)bh*32 + (n0 >> 6))*64 + d)*64 + (n0 & 63)) = s4;
            } else {
                #pragma unroll
                for (int reg = 0; reg < 4; reg++) {
                    float v = acc[tm][tn][reg] + bv;
                    if (which == 0) v *= SCLQ;
                    short* dst = (which == 0) ? Qb : Kb;
                    dst[((size_t)bh*2048 + n0 + reg)*64 + d] = f2bf(v);
                }
            }
        }
    }
}

// ---------------------------------------------------------------------------
// Flash attention R22 = R19 (best measured): R15 compute, compile-time
// buffer rotation via 10x3 macro-unrolled steps, 4 running DMA pointers.
// WMODE: 0 = vmcnt(4)+barrier (steady), 1 = vmcnt(0)+barrier, 2 = none.
// ---------------------------------------------------------------------------
#define ATTN_STEP(P, PB, DO_PRE, WMODE) do {                                   \
    if (DO_PRE) {                                                              \
        gl_lds16(pK0, Ks[PB] + c0 * 8);                                        \
        gl_lds16(pV0, Vs[PB] + c0 * 8);                                        \
        gl_lds16(pK1, Ks[PB] + c1 * 8);                                        \
        gl_lds16(pV1, Vs[PB] + c1 * 8);                                        \
        pK0 += 4096; pV0 += 4096; pK1 += 4096; pV1 += 4096;                    \
    }                                                                          \
    f32x4 st[4];                                                               \
    _Pragma("unroll")                                                          \
    for (int kvs = 0; kvs < 4; kvs++) st[kvs] = (f32x4){0.f, 0.f, 0.f, 0.f};   \
    _Pragma("unroll")                                                          \
    for (int ks = 0; ks < 2; ks++) {                                           \
        _Pragma("unroll")                                                      \
        for (int kvs = 0; kvs < 4; kvs++) {                                    \
            bf16x8 kf = *(const bf16x8*)(Ks[P] + (kvs*16 + lcol) * 64 +        \
                                         (((ks*4 + quad) ^ ksw) << 3));        \
            st[kvs] = __builtin_amdgcn_mfma_f32_16x16x32_bf16(kf, qf[ks],      \
                                                              st[kvs], 0, 0, 0); \
        }                                                                      \
    }                                                                          \
    uint32_t X[4], Y[4];                                                       \
    _Pragma("unroll")                                                          \
    for (int kvs = 0; kvs < 4; kvs++) {                                        \
        float p0 = exp2fast(st[kvs][0]), p1 = exp2fast(st[kvs][1]);            \
        float p2 = exp2fast(st[kvs][2]), p3 = exp2fast(st[kvs][3]);            \
        lp += (p0 + p1) + (p2 + p3);                                           \
        asm("v_cvt_pk_bf16_f32 %0, %1, %2" : "=v"(X[kvs]) : "v"(p0), "v"(p1)); \
        asm("v_cvt_pk_bf16_f32 %0, %1, %2" : "=v"(Y[kvs]) : "v"(p2), "v"(p3)); \
    }                                                                          \
    bf16x8 pa[2];                                                              \
    _Pragma("unroll")                                                          \
    for (int ks = 0; ks < 2; ks++) {                                           \
        uint32_t a0 = X[2*ks], a1 = X[2*ks + 1];                               \
        uint32_t b0 = Y[2*ks], b1 = Y[2*ks + 1];                               \
        asm("v_permlane16_swap_b32 %0, %1" : "+v"(a0), "+v"(a1));              \
        asm("v_permlane16_swap_b32 %0, %1" : "+v"(b0), "+v"(b1));              \
        union { uint32_t u[4]; bf16x8 v; } pk_;                                \
        pk_.u[0] = a0; pk_.u[1] = b0; pk_.u[2] = a1; pk_.u[3] = b1;            \
        pa[ks] = pk_.v;                                                        \
    }                                                                          \
    _Pragma("unroll")                                                          \
    for (int ks = 0; ks < 2; ks++) {                                           \
        _Pragma("unroll")                                                      \
        for (int tn = 0; tn < 4; tn++) {                                       \
            int row = tn * 16 + lcol;                                          \
            bf16x8 bv = *(const bf16x8*)(Vs[P] + row * 64 +                    \
                                         (((ks*4 + bq) ^ (row & 7)) << 3));    \
            o[tn] = __builtin_amdgcn_mfma_f32_16x16x32_bf16(pa[ks], bv,        \
                                                            o[tn], 0, 0, 0);   \
        }                                                                      \
    }                                                                          \
    if (WMODE == 0) { WAITCNT_VM(4); BARRIER_FENCED(); }                       \
    else if (WMODE == 1) { WAITCNT_VM(0); BARRIER_FENCED(); }                  \
} while (0)

__global__ __launch_bounds__(256)
void attn_k(const short* __restrict__ Q, const short* __restrict__ K,
            const short* __restrict__ Vt, short* __restrict__ Ab)
{
    __shared__ __align__(16) short Ks[3][4096];   // [kv][d] xor-swizzled chunks
    __shared__ __align__(16) short Vs[3][4096];   // [d][kv] xor-swizzled chunks

    const int tid = threadIdx.x, lane = tid & 63, w = tid >> 6;
    const int quad = lane >> 4, lcol = lane & 15;
    const int bid = blockIdx.x;
    const int bh = bid % 24, qt = bid / 24;
    const int b = bh / 12, h = bh - b * 12;

    const short* Kg = K  + (size_t)bh * 131072;   // [n][d] rows, tile = 8KB
    const short* Vg = Vt + (size_t)bh * 131072;   // tiled [kt][d][n64], 8KB

    bf16x8 qf[2];                       // this wave's 16 q rows only
    {
        const short* Qg = Q + ((size_t)bh * 2048 + (size_t)qt * 64) * 64;
        #pragma unroll
        for (int ks = 0; ks < 2; ks++)
            qf[ks] = *(const bf16x8*)(Qg + (w*16 + lcol) * 64 + ks*32 + quad*8);
    }

    // per-thread chunk mapping (c0: chunks 0..511, c1: 512..1023 of each tile)
    const int c0 = tid, c1 = tid + 256;
    const int r0 = c0 >> 3, s0 = r0 * 64 + (((c0 & 7) ^ (r0 & 7)) << 3);
    const int r1 = c1 >> 3, s1 = r1 * 64 + (((c1 & 7) ^ (r1 & 7)) << 3);

    // stage tiles 0,1 (4 loads/thread/tile, uniform)
    #pragma unroll
    for (int t0 = 0; t0 < 2; t0++) {
        gl_lds16(Kg + t0 * 4096 + s0, Ks[t0] + c0 * 8);
        gl_lds16(Vg + t0 * 4096 + s0, Vs[t0] + c0 * 8);
        gl_lds16(Kg + t0 * 4096 + s1, Ks[t0] + c1 * 8);
        gl_lds16(Vg + t0 * 4096 + s1, Vs[t0] + c1 * 8);
    }
    WAITCNT_VM(4);                     // Q loads + tile 0 landed; tile 1 in flight
    BARRIER_FENCED();

    // running prefetch source pointers (tile kt+2), advance 1 tile per step
    const short* pK0 = Kg + 2 * 4096 + s0;
    const short* pV0 = Vg + 2 * 4096 + s0;
    const short* pK1 = Kg + 2 * 4096 + s1;
    const short* pV1 = Vg + 2 * 4096 + s1;

    f32x4 o[4];
    #pragma unroll
    for (int tn = 0; tn < 4; tn++) o[tn] = (f32x4){0.f, 0.f, 0.f, 0.f};
    float lp = 0.f;

    const int ksw = lcol & 7;                       // K row-xor ((kvs*16+lcol)&7)
    const int bq  = ((quad & 1) << 1) | (quad >> 1); // V chunk bit-reverse perm

    for (int g = 0; g < 10; g++) {      // kt = 3g+0, 3g+1, 3g+2  (0..29)
        ATTN_STEP(0, 2, true, 0);
        ATTN_STEP(1, 0, true, 0);
        ATTN_STEP(2, 1, true, 0);
    }
    ATTN_STEP(0, 0, false, 1);          // kt = 30: drain tile 31
    ATTN_STEP(1, 0, false, 2);          // kt = 31: last, no barrier

    // row-sum: kv-split is across quads of the SAME wave -> pure shuffles
    lp += __shfl_xor(lp, 16, 64);
    lp += __shfl_xor(lp, 32, 64);
    float rl[4];
    #pragma unroll
    for (int r = 0; r < 4; r++)
        rl[r] = 1.0f / __shfl(lp, quad * 4 + r, 64);   // lane lcol=q' holds sum(q')

    #pragma unroll
    for (int tn = 0; tn < 4; tn++) {
        #pragma unroll
        for (int r = 0; r < 4; r++) {
            int q = qt * 64 + w * 16 + quad * 4 + r;
            int d = h * 64 + tn * 16 + lcol;
            Ab[((size_t)(b * 2048 + q)) * 768 + d] = f2bf(o[tn][r] * rl[r]);
        }
    }
}

// ---------------------------------------------------------------------------
// out-proj GEMM R22: 64x96 tiles, 512 blocks = 2/CU (grid-capped), XCD panel
// remap, 5-BUFFER / DISTANCE-3 / BARRIER-EVERY-2 with counted vmcnt:
// prologue stages tiles 0,1,2 (vmcnt(L): 0,1 landed, 2 in flight); round it
// reads buf it%5, prefetches tile it+3 into (it+3)%5 (it<21); barrier+
// vmcnt(L) at end of ODD rounds only (vmcnt(0) at it=21 tail).
// Invariant: after odd-round vmcnt(L), only that round's loads remain in
// flight -> reads at it+1/it+2 (tiles issued at it-2/it-1) always landed;
// issue@it overwrites buffer read@it-2, covered by barrier end of it-1/it-2.
// ---------------------------------------------------------------------------
__global__ __launch_bounds__(256)
void gemm_out(const short* __restrict__ A, const short* __restrict__ Bt,
              const float* __restrict__ bias, float* __restrict__ Of)
{
    __shared__ short As[5][64 * 32];   // 4KB per buffer (20KB)
    __shared__ short Bs[5][96 * 32];   // 6KB per buffer (30KB)
    const int tid = threadIdx.x, lane = tid & 63, w = tid >> 6;
    const int wm = w >> 1, wn = w & 1, quad = lane >> 4, lcol = lane & 15;

    // XCD-panel-grouped remap (bijective: 512 = 8 XCD * 8 bm * 8 bn)
    const int id = blockIdx.x;
    const int xcd = id & 7, j = id >> 3;
    const int bm = (xcd * 8 + (j >> 3)) * 64;
    const int bn = (j & 7) * 96;

    f32x4 acc[2][3];
    #pragma unroll
    for (int i = 0; i < 2; i++)
        #pragma unroll
        for (int jj = 0; jj < 3; jj++) acc[i][jj] = (f32x4){0.f, 0.f, 0.f, 0.f};

    const int ar0 = tid >> 2, ac0 = (tid & 3) * 8;
    const int c2  = 256 + tid;         // only tid<128 uses it
    const int br1 = c2 >> 2,  bc1 = (c2 & 3) * 8;

    const short* pA0 = A  + (size_t)(bm + ar0) * 768 + ac0;
    const short* pB0 = Bt + (size_t)(bn + ar0) * 768 + ac0;
    const short* pB1 = Bt + (size_t)(bn + br1) * 768 + bc1;

    #pragma unroll
    for (int t0 = 0; t0 < 3; t0++) {   // stage tiles 0,1,2
        const int kt = t0 * 32;
        gl_lds16(pA0 + kt, As[t0] + tid * 8);
        gl_lds16(pB0 + kt, Bs[t0] + tid * 8);
        if (tid < 128)
            gl_lds16(pB1 + kt, Bs[t0] + c2 * 8);
    }
    if (w < 2) { WAITCNT_VM(3); } else { WAITCNT_VM(2); }   // 0,1 landed; 2 in flight
    BARRIER_FENCED();

    #pragma unroll
    for (int it = 0; it < 24; it++) {
        const int p = it % 5;
        if (it < 21) {                 // prefetch tile it+3 (constants after unroll)
            const int pb = (it + 3) % 5, kt = (it + 3) * 32;
            gl_lds16(pA0 + kt, As[pb] + tid * 8);
            gl_lds16(pB0 + kt, Bs[pb] + tid * 8);
            if (tid < 128)
                gl_lds16(pB1 + kt, Bs[pb] + c2 * 8);
        }
        bf16x8 a[2], b[3];
        #pragma unroll
        for (int tm = 0; tm < 2; tm++)
            a[tm] = *(const bf16x8*)(As[p] + (wm*32 + tm*16 + lcol) * 32 + quad * 8);
        #pragma unroll
        for (int tn = 0; tn < 3; tn++)
            b[tn] = *(const bf16x8*)(Bs[p] + (wn*48 + tn*16 + lcol) * 32 + quad * 8);
        #pragma unroll
        for (int tm = 0; tm < 2; tm++)
            #pragma unroll
            for (int tn = 0; tn < 3; tn++)
                acc[tm][tn] = __builtin_amdgcn_mfma_f32_16x16x32_bf16(a[tm], b[tn], acc[tm][tn], 0, 0, 0);
        if ((it & 1) && it <= 21) {    // barrier every 2 rounds
            if (it < 21) {
                if (w < 2) { WAITCNT_VM(3); } else { WAITCNT_VM(2); }
            } else {
                WAITCNT_VM(0);         // it=21: drain tail (tiles 22,23 staged)
            }
            BARRIER_FENCED();
        }
    }
    #pragma unroll
    for (int tm = 0; tm < 2; tm++) {
        #pragma unroll
        for (int tn = 0; tn < 3; tn++) {
            int col = bn + wn*48 + tn*16 + lcol;
            float bv = bias[col];
            #pragma unroll
            for (int reg = 0; reg < 4; reg++) {
                int row = bm + wm*32 + tm*16 + quad*4 + reg;
                Of[(size_t)row * 768 + col] = acc[tm][tn][reg] + bv;
            }
        }
    }
}

// ---------------------------------------------------------------------------
extern "C" void kernel_launch(void* const* d_in, const int* in_sizes, int n_in,
                              void* d_out, int out_size, void* d_ws, size_t ws_size,
                              hipStream_t stream)
{
    (void)in_sizes; (void)n_in; (void)out_size;
    const float* x     = (const float*)d_in[0];
    const float* w_qkv = (const float*)d_in[1];
    const float* b_qkv = (const float*)d_in[2];
    const float* w_out = (const float*)d_in[3];
    const float* b_out = (const float*)d_in[4];
    float* out = (float*)d_out;

    const size_t XSZ = (size_t)4096 * 768;
    const size_t WQ  = (size_t)2304 * 768;
    const size_t WO  = (size_t)768 * 768;
    const size_t HSZ = (size_t)24 * 2048 * 64;
    short* Xb  = (short*)d_ws;
    short* Wqt = Xb + XSZ;
    short* Qb  = Wqt + WQ;
    short* Kb  = Qb + HSZ;
    short* Vt  = Kb + HSZ;
    short* Ab  = Xb;                       // x dead after gemm_qkv

    const bool sepWot = ws_size >= (XSZ + WQ + 3*HSZ + WO) * sizeof(short);
    short* Wot = sepWot ? (Vt + HSZ) : Wqt;   // else alias (w_qkv^T dead after gemm0)

    if (sepWot) {
        prep_k<<<2112, 256, 0, stream>>>(x, Xb, w_qkv, Wqt, w_out, Wot);
        gemm_qkv<<<768, 256, 0, stream>>>(Xb, Wqt, b_qkv, Qb, Kb, Vt);
    } else {
        prep_k<<<1968, 256, 0, stream>>>(x, Xb, w_qkv, Wqt, w_out, Wot);
        gemm_qkv<<<768, 256, 0, stream>>>(Xb, Wqt, b_qkv, Qb, Kb, Vt);
        tr_w<<<dim3(12, 12), 256, 0, stream>>>(w_out, Wot, 768, 768);
    }
    attn_k<<<768, 256, 0, stream>>>(Qb, Kb, Vt, Ab);
    gemm_out<<<512, 256, 0, stream>>>(Ab, Wot, b_out, out);
}